// Round 1
// baseline (90.315 us; speedup 1.0000x reference)
//
#include <hip/hip_runtime.h>
#include <hip/hip_bf16.h>

typedef __bf16 bf16x8 __attribute__((ext_vector_type(8)));
typedef float  f32x4  __attribute__((ext_vector_type(4)));

#define MFMA(a, b, c) __builtin_amdgcn_mfma_f32_16x16x32_bf16((a), (b), (c), 0, 0, 0)

// Tile: 64 edges per block-iteration. D=128, H=64, K=8 (padded to 16 in MFMA N).
// LDS: xh [64][128] bf16 (16KB) + xl (16KB) + H f32 [64][64] (16KB) = 48KB -> 3 blocks/CU.
// Row stride is 256B for all three arrays; XOR swizzle byte ^= (row&7)<<4 kills the
// 16-way ds_read_b128 bank conflict (leaves 2-way, which is free).

__device__ __forceinline__ int swz(int row, int byteInRow) {
    return row * 256 + (byteInRow ^ ((row & 7) << 4));
}

__global__ __launch_bounds__(256, 3) void edge_moe_kernel(
    const float* __restrict__ x,  const float* __restrict__ w1,
    const float* __restrict__ b1, const float* __restrict__ w2,
    const float* __restrict__ b2, const float* __restrict__ wp,
    float* __restrict__ outFused, float* __restrict__ outAlpha, int E)
{
    __shared__ __align__(16) char lds[49152];
    char* XH = lds;
    char* XL = lds + 16384;
    char* HF = lds + 32768;

    const int tid  = threadIdx.x;
    const int lane = tid & 63;
    const int wid  = tid >> 6;   // wave id 0..3
    const int lc   = lane & 15;  // fragment col / row-in-tile index
    const int lg   = lane >> 4;  // k-group 0..3

    // ---- Build weight B-fragments in registers (split bf16 hi/lo) ----
    // B-frag layout for 16x16x32: lane holds B[k = kk*32 + lg*8 + j][n = lc], j=0..7.
    bf16x8 w1h[4], w1l[4], w2h[2], w2l[2], wph[4], wpl[4];
#pragma unroll
    for (int kk = 0; kk < 4; ++kk) {
        bf16x8 h, l;
#pragma unroll
        for (int j = 0; j < 8; ++j) {
            int kidx = kk * 32 + lg * 8 + j;
            float v = w1[kidx * 64 + wid * 16 + lc];   // w1 is [128][64], wave owns n-tile wid
            __bf16 hb = (__bf16)v;
            h[j] = hb; l[j] = (__bf16)(v - (float)hb);
        }
        w1h[kk] = h; w1l[kk] = l;
    }
#pragma unroll
    for (int kk = 0; kk < 2; ++kk) {
        bf16x8 h, l;
#pragma unroll
        for (int j = 0; j < 8; ++j) {
            int kidx = kk * 32 + lg * 8 + j;
            float v = (lc < 8) ? w2[kidx * 8 + lc] : 0.0f;  // [64][8], N padded to 16
            __bf16 hb = (__bf16)v;
            h[j] = hb; l[j] = (__bf16)(v - (float)hb);
        }
        w2h[kk] = h; w2l[kk] = l;
    }
#pragma unroll
    for (int kk = 0; kk < 4; ++kk) {
        bf16x8 h, l;
#pragma unroll
        for (int j = 0; j < 8; ++j) {
            int kidx = kk * 32 + lg * 8 + j;
            float v = (lc < 8) ? wp[kidx * 8 + lc] : 0.0f;  // [128][8], N padded to 16
            __bf16 hb = (__bf16)v;
            h[j] = hb; l[j] = (__bf16)(v - (float)hb);
        }
        wph[kk] = h; wpl[kk] = l;
    }
    const float b1v = b1[wid * 16 + lc];
    const float b2v = (lc < 8) ? b2[lc] : 0.0f;

    const int ntiles = (E + 63) >> 6;
    const int r0 = tid >> 4;   // 0..15 (x-load row)
    const int c8 = tid & 15;   // 8-float column chunk

    for (int tile = blockIdx.x; tile < ntiles; tile += gridDim.x) {
        const int eb = tile * 64;

        // ---- Load x tile [64][128] f32, coalesced (issued before barrier = prefetch) ----
        float4 vr[4][2];
#pragma unroll
        for (int it = 0; it < 4; ++it) {
            int row = r0 + it * 16;
            long long e = eb + row; if (e > (long long)E - 1) e = E - 1;
            const float4* p = (const float4*)(x + (size_t)e * 128 + c8 * 8);
            vr[it][0] = p[0];
            vr[it][1] = p[1];
        }
        __syncthreads();   // prev iteration's LDS reads done

        // ---- Convert to split bf16, write LDS (swizzled) ----
#pragma unroll
        for (int it = 0; it < 4; ++it) {
            int row = r0 + it * 16;
            bf16x8 h, l;
            const float* f = (const float*)&vr[it][0];
#pragma unroll
            for (int j = 0; j < 8; ++j) {
                float v = f[j];
                __bf16 hb = (__bf16)v;
                h[j] = hb; l[j] = (__bf16)(v - (float)hb);
            }
            int off = swz(row, c8 * 16);
            *(bf16x8*)(XH + off) = h;
            *(bf16x8*)(XL + off) = l;
        }
        __syncthreads();   // x ready

        // ---- Step 2: H = relu(x @ w1 + b1). Wave owns n-tile wid; all 4 m-tiles. ----
        f32x4 acc[4];
#pragma unroll
        for (int mt = 0; mt < 4; ++mt) {
            f32x4 a = {0.f, 0.f, 0.f, 0.f};
            int row = mt * 16 + lc;  // A-frag: lane holds A[row=lc][k=kk*32+lg*8+j]
#pragma unroll
            for (int kk = 0; kk < 4; ++kk) {
                int off = swz(row, kk * 64 + lg * 16);
                bf16x8 ah = *(const bf16x8*)(XH + off);
                bf16x8 al = *(const bf16x8*)(XL + off);
                a = MFMA(ah, w1h[kk], a);
                a = MFMA(al, w1h[kk], a);
                a = MFMA(ah, w1l[kk], a);
            }
            acc[mt] = a;
        }
        // bias + relu, write H f32 to LDS (C/D layout: row=lg*4+r, col=lc)
#pragma unroll
        for (int mt = 0; mt < 4; ++mt) {
#pragma unroll
            for (int r = 0; r < 4; ++r) {
                float hv = fmaxf(acc[mt][r] + b1v, 0.f);
                int row = mt * 16 + lg * 4 + r;
                int col = wid * 16 + lc;
                *(float*)(HF + swz(row, col * 4)) = hv;
            }
        }
        __syncthreads();   // H ready (x still valid)

        // ---- Steps 3/4: wave owns m-tile wid. logits = H@w2 + b2; scores = x@wp ----
        f32x4 lac = {0.f, 0.f, 0.f, 0.f};
        f32x4 sac = {0.f, 0.f, 0.f, 0.f};
        {
            int row = wid * 16 + lc;
#pragma unroll
            for (int kk = 0; kk < 2; ++kk) {
                int base = kk * 128 + lg * 32;     // f32 bytes: k = kk*32 + lg*8
                f32x4 h0 = *(const f32x4*)(HF + swz(row, base));
                f32x4 h1 = *(const f32x4*)(HF + swz(row, base + 16));
                bf16x8 hh, hl;
#pragma unroll
                for (int j = 0; j < 4; ++j) {
                    float v0 = h0[j]; __bf16 q0 = (__bf16)v0;
                    hh[j] = q0; hl[j] = (__bf16)(v0 - (float)q0);
                    float v1 = h1[j]; __bf16 q1 = (__bf16)v1;
                    hh[j + 4] = q1; hl[j + 4] = (__bf16)(v1 - (float)q1);
                }
                lac = MFMA(hh, w2h[kk], lac);
                lac = MFMA(hl, w2h[kk], lac);
                lac = MFMA(hh, w2l[kk], lac);
            }
#pragma unroll
            for (int kk = 0; kk < 4; ++kk) {
                int off = swz(row, kk * 64 + lg * 16);
                bf16x8 ah = *(const bf16x8*)(XH + off);
                bf16x8 al = *(const bf16x8*)(XL + off);
                sac = MFMA(ah, wph[kk], sac);
                sac = MFMA(al, wph[kk], sac);
                sac = MFMA(ah, wpl[kk], sac);
            }
        }

        // ---- Softmax over 8 cols (lanes c=0..7 within 16-lane group) + fused dot ----
#pragma unroll
        for (int r = 0; r < 4; ++r) {
            float lv = lac[r] + b2v;           // TEMPERATURE = 1.0
            float m = lv;
            m = fmaxf(m, __shfl_xor(m, 1));
            m = fmaxf(m, __shfl_xor(m, 2));
            m = fmaxf(m, __shfl_xor(m, 4));
            float p = __expf(lv - m);
            float s = p;
            s += __shfl_xor(s, 1);
            s += __shfl_xor(s, 2);
            s += __shfl_xor(s, 4);
            float alpha = p / s;
            float fv = alpha * sac[r];
            fv += __shfl_xor(fv, 1);
            fv += __shfl_xor(fv, 2);
            fv += __shfl_xor(fv, 4);
            long long edge = eb + wid * 16 + lg * 4 + r;
            if (edge < E) {
                if (lc < 8) outAlpha[edge * 8 + lc] = alpha;
                if (lc == 0) outFused[edge] = fv;
            }
        }
    }
}

extern "C" void kernel_launch(void* const* d_in, const int* in_sizes, int n_in,
                              void* d_out, int out_size, void* d_ws, size_t ws_size,
                              hipStream_t stream) {
    const float* x  = (const float*)d_in[0];
    const float* w1 = (const float*)d_in[1];
    const float* b1 = (const float*)d_in[2];
    const float* w2 = (const float*)d_in[3];
    const float* b2 = (const float*)d_in[4];
    const float* wp = (const float*)d_in[5];

    const int E = in_sizes[0] / 128;
    float* outF = (float*)d_out;
    float* outA = outF + E;

    const int ntiles = (E + 63) >> 6;
    const int blocks = ntiles < 768 ? ntiles : 768;
    edge_moe_kernel<<<blocks, 256, 0, stream>>>(x, w1, b1, w2, b2, wp, outF, outA, E);
}